// Round 1
// baseline (161.872 us; speedup 1.0000x reference)
//
#include <hip/hip_runtime.h>
#include <hip/hip_bf16.h>
#include <hip/hip_fp8.h>
#include <stdint.h>

// Shapes: b=2, n=5, k=5, q=75, t=196, c=384, s=k*t=980 (padded to 1024/class)
// M per b = 75*196 = 14700 (58 tiles of 256 rows). Outputs: logits[750] ++ cls_logits[750].
// Sim branch: fp8-e4m3 MX-scaled MFMA (scales=1.0); cls branch exact fp32.
// gemm: A register-resident (256 rows/block, 64/wave), B streamed once per block-half
// via ASYNC global_load_lds DMA into a TRIPLE-buffered LDS (36 KB), ONE raw s_barrier +
// counted s_waitcnt vmcnt(3) per 32-col chunk (never a full drain in the main loop).
// Round-10 change: the old path staged B through VGPRs (global->nx regs->ds_write->
// __syncthreads). That cost 192 ds_write_b128/block on the LDS pipe, a compiler-emitted
// vmcnt(0)+lgkmcnt(0) full drain at every barrier, and ~12 VGPRs of staging registers —
// counters showed MfmaUtil 32.5% / VALUBusy 30% / LDS-conflict 3.1K cyc/block with both
// pipes idle ~2/3 of the time (pipeline-bound, not roofline-bound). global_load_lds works
// here because the swizzle was ALREADY folded into the per-lane GLOBAL source offsets
// (src_off[]) with a linear LDS destination (tid*16) — exactly the wave-uniform-base +
// lane*16 layout the DMA writes (guide m173 / rule #21).
// Triple-buffer safety: buffer (i+1)%3 written at iter i was last READ at compute i-2;
// barrier(i-1) sits between all waves' compute(i-2) and my issue(i). Each wave does
// vmcnt(3) (drain oldest chunk, leave the newly issued one in flight) BEFORE barrier(i),
// so after barrier(i) chunk i is landed workgroup-wide.
// Register discipline (round-8/9 lesson): 64-col chunks (nx[6] + wide addressing) push
// the allocator past its 128-VGPR split -> ~80 MB scratch spill traffic. Keep 32-col
// chunks; the DMA path only removes registers, never adds.

typedef __attribute__((ext_vector_type(8))) int int8v;      // f8f6f4 A/B operand (32 fp8)
typedef __attribute__((ext_vector_type(4))) float f32x4;    // MFMA C/D frag

__device__ __forceinline__ unsigned enc_f(float f) {
    unsigned b = __float_as_uint(f);
    return (b & 0x80000000u) ? ~b : (b | 0x80000000u);
}
__device__ __forceinline__ float dec_f(unsigned u) {
    unsigned b = (u & 0x80000000u) ? (u & 0x7FFFFFFFu) : ~u;
    return __uint_as_float(b);
}

__device__ __forceinline__ unsigned pack4_fp8(float a, float b, float c, float d) {
    int r = __builtin_amdgcn_cvt_pk_fp8_f32(a, b, 0, false);   // bytes 0,1
    r = __builtin_amdgcn_cvt_pk_fp8_f32(c, d, r, true);        // bytes 2,3
    return (unsigned)r;
}

// async 16B global->LDS DMA (gfx950). size must be a literal; dest is wave-uniform
// base + lane*16 (hardware scatter), source address is per-lane.
__device__ __forceinline__ void gload_lds16(const uint8_t* g, uint8_t* l) {
    __builtin_amdgcn_global_load_lds((const __attribute__((address_space(1))) void*)g,
                                     (__attribute__((address_space(3))) void*)l,
                                     16, 0, 0);
}

// ---------------- fused prep: norm (16 lanes/row) | proto | init_P ----------------
__global__ void prep_kernel(const float* __restrict__ feat_query,
                            const float* __restrict__ feat_shot,
                            const float* __restrict__ x_shot,
                            unsigned* __restrict__ fqn,
                            unsigned* __restrict__ fsnp,
                            float* __restrict__ proto,
                            unsigned* __restrict__ P) {
    const int blk  = blockIdx.x;
    const int tid  = threadIdx.x;
    const int lane = tid & 63;
    const int wv   = tid >> 6;

    if (blk < 2478) {                       // ---- token L2 norm -> fp8, 4 rows/wave ----
        const int tr  = blk * 16 + wv * 4 + (lane >> 4);   // 0..39639
        const int l16 = lane & 15;
        if (tr >= 39640) return;

        const float* row;
        unsigned* o32;
        bool zero = false;
        if (tr < 29400) {
            row = feat_query + (size_t)tr * 384;
            o32 = fqn + (size_t)tr * 96;
        } else {
            const int sp = tr - 29400;          // padded shot row: [bn][1024]
            const int bn = sp >> 10;
            const int s  = sp & 1023;
            o32 = fsnp + (size_t)sp * 96;
            row = feat_shot + ((size_t)bn * 980 + s) * 384;
            zero = (s >= 980);
        }
        if (zero) {
#pragma unroll
            for (int j = 0; j < 6; ++j) o32[l16 + 16 * j] = 0u;
            return;
        }
        const float4* rf4 = (const float4*)row;
        float4 v[6];
        float ss = 0.f;
#pragma unroll
        for (int j = 0; j < 6; ++j) {
            v[j] = rf4[l16 + 16 * j];
            ss += v[j].x * v[j].x + v[j].y * v[j].y + v[j].z * v[j].z + v[j].w * v[j].w;
        }
#pragma unroll
        for (int off = 1; off < 16; off <<= 1) ss += __shfl_xor(ss, off, 64);
        const float sc = 1.0f / fmaxf(sqrtf(ss), 1e-8f);
#pragma unroll
        for (int j = 0; j < 6; ++j)
            o32[l16 + 16 * j] = pack4_fp8(v[j].x * sc, v[j].y * sc, v[j].z * sc, v[j].w * sc);
    } else if (blk < 2481) {                // ---- proto = l2norm(mean_k x_shot), fp32 ----
        const int gw = (blk - 2478) * 4 + wv;
        if (gw >= 10) return;
        const float* base = x_shot + (size_t)gw * 5 * 384;
        float v[6];
        float ss = 0.f;
#pragma unroll
        for (int j = 0; j < 6; ++j) {
            float s = 0.f;
#pragma unroll
            for (int kk = 0; kk < 5; ++kk) s += base[kk * 384 + lane + 64 * j];
            s *= 0.2f;
            v[j] = s;
            ss += s * s;
        }
#pragma unroll
        for (int off = 1; off < 64; off <<= 1) ss += __shfl_xor(ss, off, 64);
        const float scale = 1.0f / fmaxf(sqrtf(ss), 1e-12f);
#pragma unroll
        for (int j = 0; j < 6; ++j) proto[(size_t)gw * 384 + lane + 64 * j] = v[j] * scale;
    } else {                                // ---- init P to encoded -inf (0) ----
        const int i = (blk - 2481) * 256 + tid;
        if (i < 147000) P[i] = 0u;
    }
}

// ---------------- fp8 GEMM + row-max: 256 A-rows in regs, half-class B via async LDS ----------------
// grid = 2b x 5cls x 2sh x 58mt = 1160 blocks; 256 thr = 4 waves (64 rows each).
// B chunk = 32 cols x 384 B = 12 KB; 16 chunks per half-class; triple-buffered (36 KB LDS).
// Loop: issue async DMA for chunk it+1 -> buf[nxt]  (overlaps everything below)
//       s_waitcnt vmcnt(3)   (drains chunk it, leaves chunk it+1 in flight)
//       raw s_barrier        (now chunk it is visible workgroup-wide)
//       compute chunk it from buf[cur]  (3 ks x [2 B-frags, 8 MFMA])
// LDS layout: [col][24 granules of 16B], slot g' holds source granule
// (g'&~7)|((g'&7)^(col&7)) — the XOR swizzle lives in the GLOBAL src offsets, the LDS
// dest is linear tid*16 (DMA-compatible); frag reads hit bank quadrant (2hi+c)^(l15&7).
__global__ __launch_bounds__(256, 2) void gemm_kernel(const uint8_t* __restrict__ fqn,
                                                      const uint8_t* __restrict__ fsnp,
                                                      unsigned* __restrict__ P) {
    __shared__ __align__(16) uint8_t Bl[3][12288];   // 36 KB triple buffer

    const int bid = blockIdx.x;       // (((b*5+cls)*2)+sh)*58 + mt
    const int mt  = bid % 58;
    const int g1  = bid / 58;
    const int sh  = g1 & 1;
    const int bc  = g1 >> 1;          // b*5+cls
    const int b   = bc / 5;
    const int m0  = mt * 256;

    const int tid  = threadIdx.x;
    const int lane = tid & 63;
    const int wv   = tid >> 6;
    const int l15  = lane & 15;
    const int hi   = lane >> 4;

    const uint8_t* Ag = fqn  + (size_t)b * 14700 * 384;
    const uint8_t* Bg = fsnp + ((size_t)bc * 1024 + sh * 512) * 384;

    // ---- A fragments -> registers (one-time; wave wv holds rows m0+wv*64 .. +63) ----
    int8v A[4][3];
#pragma unroll
    for (int mi = 0; mi < 4; ++mi) {
        int row = m0 + wv * 64 + mi * 16 + l15;
        row = row < 14700 ? row : 14699;           // clamp; dead rows masked at epilogue
        const uint8_t* pa = Ag + (size_t)row * 384 + hi * 32;
#pragma unroll
        for (int ks = 0; ks < 3; ++ks) {
            const uint4 x = *(const uint4*)(pa + ks * 128);
            const uint4 y = *(const uint4*)(pa + ks * 128 + 16);
            A[mi][ks] = (int8v){(int)x.x, (int)x.y, (int)x.z, (int)x.w,
                                (int)y.x, (int)y.y, (int)y.z, (int)y.w};
        }
    }

    // ---- staging addresses: 3 granules of 16B per thread per 32-col chunk ----
    // src_off carries the XOR swizzle; LDS destination is linear (DMA lane*16).
    int src_off[3];
#pragma unroll
    for (int rr = 0; rr < 3; ++rr) {
        const int idx = rr * 256 + tid;            // 0..767 slots
        const int col = idx / 24;
        const int gp  = idx - col * 24;
        const int g   = (gp & ~7) | ((gp & 7) ^ (col & 7));
        src_off[rr] = col * 384 + g * 16;
    }

    // ---- prologue: issue chunk 0 DMA into buffer 0 ----
#pragma unroll
    for (int rr = 0; rr < 3; ++rr)
        gload_lds16(Bg + src_off[rr], &Bl[0][rr * 4096 + wv * 1024]);

    float rmax[4][4];
#pragma unroll
    for (int mi = 0; mi < 4; ++mi)
#pragma unroll
        for (int i = 0; i < 4; ++i) rmax[mi][i] = -3.0e38f;

    const int c0 = ((2 * hi + 0) ^ (l15 & 7)) * 16;
    const int c1 = ((2 * hi + 1) ^ (l15 & 7)) * 16;

    int cur = 0;
    for (int it = 0; it < 16; ++it) {
        const int nxt = (cur == 2) ? 0 : cur + 1;

        // issue next chunk's DMA (lands any time before the NEXT iteration's barrier);
        // counted vmcnt: drain chunk it (oldest 3), keep chunk it+1 in flight.
        if (it + 1 < 16) {
            const uint8_t* src = Bg + (size_t)(it + 1) * 12288;
#pragma unroll
            for (int rr = 0; rr < 3; ++rr)
                gload_lds16(src + src_off[rr], &Bl[nxt][rr * 4096 + wv * 1024]);
            asm volatile("s_waitcnt vmcnt(3)" ::: "memory");
        } else {
            asm volatile("s_waitcnt vmcnt(0)" ::: "memory");
        }
        __builtin_amdgcn_s_barrier();
        asm volatile("" ::: "memory");   // fence: keep ds_reads below the barrier

        // compute on buffer cur (chunk it)
        const uint8_t* buf = Bl[cur];
        f32x4 acc[4][2];
#pragma unroll
        for (int mi = 0; mi < 4; ++mi)
#pragma unroll
            for (int nf = 0; nf < 2; ++nf) acc[mi][nf] = (f32x4){0.f, 0.f, 0.f, 0.f};

#pragma unroll
        for (int ks = 0; ks < 3; ++ks) {
            int8v Bf[2];
#pragma unroll
            for (int nf = 0; nf < 2; ++nf) {
                const uint8_t* base = buf + (nf * 16 + l15) * 384 + ks * 128;
                const uint4 x = *(const uint4*)(base + c0);
                const uint4 y = *(const uint4*)(base + c1);
                Bf[nf] = (int8v){(int)x.x, (int)x.y, (int)x.z, (int)x.w,
                                 (int)y.x, (int)y.y, (int)y.z, (int)y.w};
            }
#pragma unroll
            for (int mi = 0; mi < 4; ++mi)
#pragma unroll
                for (int nf = 0; nf < 2; ++nf)
                    acc[mi][nf] = __builtin_amdgcn_mfma_scale_f32_16x16x128_f8f6f4(
                        A[mi][ks], Bf[nf], acc[mi][nf],
                        0, 0,                    // cbsz=fp8(e4m3), blgp=fp8(e4m3)
                        0, 0x7F7F7F7F,           // scale_a = 1.0
                        0, 0x7F7F7F7F);          // scale_b = 1.0
        }

        // fold row-max (mask padded cols >= 980)
#pragma unroll
        for (int nf = 0; nf < 2; ++nf) {
            if (sh * 512 + it * 32 + nf * 16 + l15 < 980) {
#pragma unroll
                for (int mi = 0; mi < 4; ++mi)
#pragma unroll
                    for (int i = 0; i < 4; ++i)
                        rmax[mi][i] = fmaxf(rmax[mi][i], acc[mi][nf][i]);
            }
        }
        cur = nxt;
    }

    // ---- epilogue: max over the 16 col-lanes, then device-scope atomicMax ----
#pragma unroll
    for (int mi = 0; mi < 4; ++mi)
#pragma unroll
        for (int i = 0; i < 4; ++i) {
            float v = rmax[mi][i];
#pragma unroll
            for (int off = 1; off < 16; off <<= 1) v = fmaxf(v, __shfl_xor(v, off, 64));
            if (l15 == 0) {
                const int row = m0 + wv * 64 + mi * 16 + hi * 4 + i;
                if (row < 14700)
                    atomicMax(&P[(size_t)bc * 14700 + row], enc_f(v));
            }
        }
}

// ---------------- fused final: logits (mean over t of row maxima) | cls_logits ----------------
__global__ void final_kernel(const unsigned* __restrict__ P,
                             const float* __restrict__ xq,
                             const float* __restrict__ proto,
                             float* __restrict__ out) {
    const int blk  = blockIdx.x;
    const int tid  = threadIdx.x;
    const int lane = tid & 63;
    const int wv   = tid >> 6;

    if (blk < 188) {                        // ---- logits ----
        const int gw = blk * 4 + wv;        // (b*75+q)*5+n
        if (gw >= 750) return;
        const int n  = gw % 5;
        const int bq = gw / 5;
        const int b  = bq / 75;
        const int q  = bq % 75;
        const unsigned* row = P + (size_t)(b * 5 + n) * 14700 + q * 196;
        float s = 0.f;
        for (int t = lane; t < 196; t += 64) s += dec_f(row[t]);
#pragma unroll
        for (int off = 1; off < 64; off <<= 1) s += __shfl_xor(s, off, 64);
        if (lane == 0) out[gw] = s * (1.0f / 196.0f);
    } else {                                // ---- cls_logits ----
        const int gw = (blk - 188) * 4 + wv;   // b*75+q
        if (gw >= 150) return;
        const float* row = xq + (size_t)gw * 384;
        float u[6];
        float ss = 0.f;
#pragma unroll
        for (int j = 0; j < 6; ++j) { u[j] = row[lane + 64 * j]; ss += u[j] * u[j]; }
#pragma unroll
        for (int off = 1; off < 64; off <<= 1) ss += __shfl_xor(ss, off, 64);
        const float scale = 1.0f / fmaxf(sqrtf(ss), 1e-12f);
#pragma unroll
        for (int j = 0; j < 6; ++j) u[j] *= scale;
        const int b = gw / 75;
        for (int n = 0; n < 5; ++n) {
            const float* p = proto + (size_t)(b * 5 + n) * 384;
            float d = 0.f;
#pragma unroll
            for (int j = 0; j < 6; ++j) d += u[j] * p[lane + 64 * j];
#pragma unroll
            for (int off = 1; off < 64; off <<= 1) d += __shfl_xor(d, off, 64);
            if (lane == 0) out[750 + gw * 5 + n] = 10.0f * d;
        }
    }
}

extern "C" void kernel_launch(void* const* d_in, const int* in_sizes, int n_in,
                              void* d_out, int out_size, void* d_ws, size_t ws_size,
                              hipStream_t stream) {
    const float* feat_shot  = (const float*)d_in[0];  // [2,5,5,196,384]
    const float* feat_query = (const float*)d_in[1];  // [2,75,196,384]
    const float* x_shot     = (const float*)d_in[2];  // [2,5,5,384]
    const float* x_query    = (const float*)d_in[3];  // [2,75,384]
    float* out = (float*)d_out;
    char* ws = (char*)d_ws;

    // ws layout (15.8 MiB total)
    uint8_t*  fqn   = (uint8_t*)ws;                     // 29400*384  = 11,289,600 B (fp8)
    uint8_t*  fsnp  = (uint8_t*)(ws + 11289600);        // 10240*384  =  3,932,160 B (fp8)
    float*    proto = (float*)(ws + 15221760);          //      3,840 f32
    unsigned* P     = (unsigned*)(ws + 15237120);       //    147,000 u32

    prep_kernel<<<3056, 256, 0, stream>>>(feat_query, feat_shot, x_shot,
                                          (unsigned*)fqn, (unsigned*)fsnp, proto, P);
    gemm_kernel<<<1160, 256, 0, stream>>>(fqn, fsnp, P);
    final_kernel<<<226, 256, 0, stream>>>(P, x_query, proto, out);
}